// Round 2
// baseline (188.853 us; speedup 1.0000x reference)
//
#include <hip/hip_runtime.h>
#include <cstdint>
#include <cstddef>

#define KTOP 10
#define BQ 4096
#define BD 32768
#define THREADS 256
#define F4_PER_ROW (BD / 4)            // 8192
#define ITERS (F4_PER_ROW / THREADS)   // 32

// Kernel 1: one block per row. Per-thread register top-10, block merge via
// LDS + 10 argmax-extraction rounds, thread 0 computes the NDCG loss term.
__global__ __launch_bounds__(THREADS) void topk_ndcg_rows(
    const float* __restrict__ scores,
    const int* __restrict__ mask,          // jnp.bool_ arrives as int32 on device
    float* __restrict__ per_row)
{
    const int row = blockIdx.x;
    const int tid = threadIdx.x;
    const float4* row4 = reinterpret_cast<const float4*>(scores + (size_t)row * BD);

    float tv[KTOP];
    int   ti[KTOP];
#pragma unroll
    for (int k = 0; k < KTOP; ++k) { tv[k] = -INFINITY; ti[k] = 0x7fffffff; }

#pragma unroll 4
    for (int i = 0; i < ITERS; ++i) {
        const int f4 = tid + i * THREADS;          // coalesced: 64 lanes x 16B
        const float4 x = row4[f4];
        const int jbase = f4 * 4;
        float vals[4] = { x.x, x.y, x.z, x.w };
#pragma unroll
        for (int c = 0; c < 4; ++c) {
            const float v = vals[c];
            const int   j = jbase + c;
            if (v > tv[KTOP - 1]) {
                bool cc[KTOP];
#pragma unroll
                for (int k = 0; k < KTOP; ++k) cc[k] = v > tv[k];
#pragma unroll
                for (int k = KTOP - 1; k >= 1; --k) {
                    tv[k] = cc[k] ? (cc[k - 1] ? tv[k - 1] : v) : tv[k];
                    ti[k] = cc[k] ? (cc[k - 1] ? ti[k - 1] : j) : ti[k];
                }
                if (cc[0]) { tv[0] = v; ti[0] = j; }
            }
        }
    }

    __shared__ float lv[THREADS][KTOP];
    __shared__ int   li[THREADS][KTOP];
    __shared__ float wv[4];
    __shared__ int   wi[4];
    __shared__ int   wt[4];
    __shared__ int   topi[KTOP];

#pragma unroll
    for (int k = 0; k < KTOP; ++k) { lv[tid][k] = tv[k]; li[tid][k] = ti[k]; }
    __syncthreads();

    int p = 0;  // how many of my entries have been extracted
    for (int r = 0; r < KTOP; ++r) {
        float cv = (p < KTOP) ? lv[tid][p] : -INFINITY;
        int   ci = (p < KTOP) ? li[tid][p] : 0x7fffffff;
        int   ct = tid;
        // 64-lane butterfly argmax; tie -> lower doc index (matches lax.top_k)
#pragma unroll
        for (int m = 32; m >= 1; m >>= 1) {
            const float ov = __shfl_xor(cv, m);
            const int   oi = __shfl_xor(ci, m);
            const int   ot = __shfl_xor(ct, m);
            const bool take = (ov > cv) || (ov == cv && oi < ci);
            cv = take ? ov : cv;
            ci = take ? oi : ci;
            ct = take ? ot : ct;
        }
        if ((tid & 63) == 0) { const int w = tid >> 6; wv[w] = cv; wi[w] = ci; wt[w] = ct; }
        __syncthreads();
        float bv = wv[0]; int bi = wi[0]; int bt = wt[0];
#pragma unroll
        for (int w = 1; w < 4; ++w) {
            const float ov = wv[w]; const int oi = wi[w]; const int ot = wt[w];
            const bool take = (ov > bv) || (ov == bv && oi < bi);
            bv = take ? ov : bv;
            bi = take ? oi : bi;
            bt = take ? ot : bt;
        }
        if (tid == bt) ++p;           // winner pops its list head
        if (tid == 0) topi[r] = bi;
        __syncthreads();
    }

    if (tid == 0) {
        float invd[KTOP];
#pragma unroll
        for (int r = 0; r < KTOP; ++r) invd[r] = 1.0f / log2f((float)(r + 2));
        const int* mrow = mask + (size_t)row * BD;
        float actual = 0.0f;
        int cnt = 0;
#pragma unroll
        for (int r = 0; r < KTOP; ++r) {
            const bool pos = (mrow[topi[r]] != 0);
            actual += pos ? invd[r] : 0.0f;
            cnt += pos ? 1 : 0;
        }
        float ideal = 0.0f;
#pragma unroll
        for (int r = 0; r < KTOP; ++r) ideal += (r < cnt) ? invd[r] : 0.0f;
        per_row[row] = (ideal > 0.0f) ? (1.0f - actual / ideal) : 0.0f;
    }
}

// Kernel 2: deterministic reduction of the 4096 per-row losses -> scalar mean.
__global__ __launch_bounds__(256) void reduce_mean(
    const float* __restrict__ per_row, float* __restrict__ out)
{
    const int tid = threadIdx.x;
    float s = 0.0f;
    for (int i = tid; i < BQ; i += 256) s += per_row[i];
#pragma unroll
    for (int m = 32; m >= 1; m >>= 1) s += __shfl_xor(s, m);
    __shared__ float ws[4];
    if ((tid & 63) == 0) ws[tid >> 6] = s;
    __syncthreads();
    if (tid == 0) out[0] = (ws[0] + ws[1] + ws[2] + ws[3]) / (float)BQ;
}

extern "C" void kernel_launch(void* const* d_in, const int* in_sizes, int n_in,
                              void* d_out, int out_size, void* d_ws, size_t ws_size,
                              hipStream_t stream) {
    const float* scores = (const float*)d_in[0];
    const int*   mask   = (const int*)d_in[1];     // bool_ -> int32 on device
    float* per_row = (float*)d_ws;                 // 4096 floats, rewritten every call

    topk_ndcg_rows<<<BQ, THREADS, 0, stream>>>(scores, mask, per_row);
    reduce_mean<<<1, 256, 0, stream>>>(per_row, (float*)d_out);
}

// Round 3
// 139.131 us; speedup vs baseline: 1.3574x; 1.3574x over previous
//
#include <hip/hip_runtime.h>
#include <cstdint>
#include <cstddef>

#define KTOP 10
#define BQ 4096
#define BD 32768
#define THREADS 256
#define F4_PER_ROW (BD / 4)            // 8192
#define ITERS (F4_PER_ROW / THREADS)   // 32
#define CAP (THREADS * KTOP)           // 2560 candidate slots (also fallback dump size)
#define T_STATIC 3.0f                  // prefilter threshold; exact fallback below if it fails

// One block per row. Fast path: static-threshold candidate collection (expected
// ~44 candidates/row for N(0,1)); exact tie-aware top-10 over candidates.
// Fallback (taken only if <KTOP candidates or overflow -> exact for ANY input):
// classic per-thread register top-10 ladder over the full row.
__global__ __launch_bounds__(THREADS) void topk_ndcg_rows(
    const float* __restrict__ scores,
    const int* __restrict__ mask,          // jnp.bool_ arrives as int32 on device
    float* __restrict__ per_row)
{
    const int row = blockIdx.x;
    const int tid = threadIdx.x;
    const float4* row4 = reinterpret_cast<const float4*>(scores + (size_t)row * BD);

    __shared__ int   s_cnt;
    __shared__ float cv[CAP];              // candidate values (later reused as merge lists)
    __shared__ int   ci[CAP];              // candidate indices
    __shared__ float wv[4];
    __shared__ int   wi[4];
    __shared__ int   wt[4];
    __shared__ int   topi[KTOP];

    if (tid == 0) s_cnt = 0;
    __syncthreads();

    // ---- Pass 1: stream the row, collect candidates >= T_STATIC ----
    for (int i = 0; i < ITERS; ++i) {
        const int f4 = tid + i * THREADS;          // coalesced 64x16B
        const float4 x = row4[f4];
        const float m = fmaxf(fmaxf(x.x, x.y), fmaxf(x.z, x.w));
        if (m >= T_STATIC) {
            const int jb = f4 * 4;
            float vs[4] = { x.x, x.y, x.z, x.w };
#pragma unroll
            for (int c = 0; c < 4; ++c) {
                if (vs[c] >= T_STATIC) {
                    const int p = atomicAdd(&s_cnt, 1);
                    if (p < CAP) { cv[p] = vs[c]; ci[p] = jb + c; }
                }
            }
        }
    }
    __syncthreads();
    int n = s_cnt;                                  // uniform across block

    if (n < KTOP || n > CAP) {
        // ---- Exact fallback: per-thread top-10 ladder over full row ----
        float tv[KTOP]; int ti[KTOP];
#pragma unroll
        for (int k = 0; k < KTOP; ++k) { tv[k] = -INFINITY; ti[k] = 0x7fffffff; }
        for (int i = 0; i < ITERS; ++i) {
            const int f4 = tid + i * THREADS;
            const float4 x = row4[f4];
            const int jb = f4 * 4;
            float vs[4] = { x.x, x.y, x.z, x.w };
#pragma unroll
            for (int c = 0; c < 4; ++c) {
                const float v = vs[c];
                const int   j = jb + c;
                if (v > tv[KTOP - 1]) {             // scan order = ascending index -> ties keep lower
                    bool cc[KTOP];
#pragma unroll
                    for (int k = 0; k < KTOP; ++k) cc[k] = v > tv[k];
#pragma unroll
                    for (int k = KTOP - 1; k >= 1; --k) {
                        tv[k] = cc[k] ? (cc[k - 1] ? tv[k - 1] : v) : tv[k];
                        ti[k] = cc[k] ? (cc[k - 1] ? ti[k - 1] : j) : ti[k];
                    }
                    if (cc[0]) { tv[0] = v; ti[0] = j; }
                }
            }
        }
        __syncthreads();                            // cv/ci candidate reads done (none), safe to overwrite
#pragma unroll
        for (int k = 0; k < KTOP; ++k) { cv[tid * KTOP + k] = tv[k]; ci[tid * KTOP + k] = ti[k]; }
        n = CAP;
        __syncthreads();
    }

    // ---- Per-thread tie-aware top-10 over the n candidates ----
    float tv[KTOP]; int ti[KTOP];
#pragma unroll
    for (int k = 0; k < KTOP; ++k) { tv[k] = -INFINITY; ti[k] = 0x7fffffff; }
    for (int p = tid; p < n; p += THREADS) {
        const float v = cv[p];
        const int   j = ci[p];
        const bool enter = (v > tv[KTOP - 1]) || (v == tv[KTOP - 1] && j < ti[KTOP - 1]);
        if (enter) {
            bool cc[KTOP];
#pragma unroll
            for (int k = 0; k < KTOP; ++k) cc[k] = (v > tv[k]) || (v == tv[k] && j < ti[k]);
#pragma unroll
            for (int k = KTOP - 1; k >= 1; --k) {
                tv[k] = cc[k] ? (cc[k - 1] ? tv[k - 1] : v) : tv[k];
                ti[k] = cc[k] ? (cc[k - 1] ? ti[k - 1] : j) : ti[k];
            }
            if (cc[0]) { tv[0] = v; ti[0] = j; }
        }
    }
    __syncthreads();                                // done reading candidates; reuse cv/ci as merge lists
#pragma unroll
    for (int k = 0; k < KTOP; ++k) { cv[tid * KTOP + k] = tv[k]; ci[tid * KTOP + k] = ti[k]; }
    __syncthreads();

    // ---- 10 block argmax-extraction rounds (tie -> lower doc index) ----
    int p = 0;
    for (int r = 0; r < KTOP; ++r) {
        float cvv = (p < KTOP) ? cv[tid * KTOP + p] : -INFINITY;
        int   cii = (p < KTOP) ? ci[tid * KTOP + p] : 0x7fffffff;
        int   ct  = tid;
#pragma unroll
        for (int m = 32; m >= 1; m >>= 1) {
            const float ov = __shfl_xor(cvv, m);
            const int   oi = __shfl_xor(cii, m);
            const int   ot = __shfl_xor(ct, m);
            const bool take = (ov > cvv) || (ov == cvv && oi < cii);
            cvv = take ? ov : cvv;
            cii = take ? oi : cii;
            ct  = take ? ot : ct;
        }
        if ((tid & 63) == 0) { const int w = tid >> 6; wv[w] = cvv; wi[w] = cii; wt[w] = ct; }
        __syncthreads();
        float bv = wv[0]; int bi = wi[0]; int bt = wt[0];
#pragma unroll
        for (int w = 1; w < 4; ++w) {
            const float ov = wv[w]; const int oi = wi[w]; const int ot = wt[w];
            const bool take = (ov > bv) || (ov == bv && oi < bi);
            bv = take ? ov : bv;
            bi = take ? oi : bi;
            bt = take ? ot : bt;
        }
        if (tid == bt) ++p;
        if (tid == 0) topi[r] = bi;
        __syncthreads();
    }

    // ---- NDCG loss term ----
    if (tid == 0) {
        float invd[KTOP];
#pragma unroll
        for (int r = 0; r < KTOP; ++r) invd[r] = 1.0f / log2f((float)(r + 2));
        const int* mrow = mask + (size_t)row * BD;
        float actual = 0.0f;
        int cnt = 0;
#pragma unroll
        for (int r = 0; r < KTOP; ++r) {
            const bool pos = (mrow[topi[r]] != 0);
            actual += pos ? invd[r] : 0.0f;
            cnt += pos ? 1 : 0;
        }
        float ideal = 0.0f;
#pragma unroll
        for (int r = 0; r < KTOP; ++r) ideal += (r < cnt) ? invd[r] : 0.0f;
        per_row[row] = (ideal > 0.0f) ? (1.0f - actual / ideal) : 0.0f;
    }
}

// Deterministic reduction of the 4096 per-row losses -> scalar mean.
__global__ __launch_bounds__(256) void reduce_mean(
    const float* __restrict__ per_row, float* __restrict__ out)
{
    const int tid = threadIdx.x;
    float s = 0.0f;
    for (int i = tid; i < BQ; i += 256) s += per_row[i];
#pragma unroll
    for (int m = 32; m >= 1; m >>= 1) s += __shfl_xor(s, m);
    __shared__ float ws[4];
    if ((tid & 63) == 0) ws[tid >> 6] = s;
    __syncthreads();
    if (tid == 0) out[0] = (ws[0] + ws[1] + ws[2] + ws[3]) / (float)BQ;
}

extern "C" void kernel_launch(void* const* d_in, const int* in_sizes, int n_in,
                              void* d_out, int out_size, void* d_ws, size_t ws_size,
                              hipStream_t stream) {
    const float* scores = (const float*)d_in[0];
    const int*   mask   = (const int*)d_in[1];     // bool_ -> int32 on device
    float* per_row = (float*)d_ws;                 // 4096 floats, rewritten every call

    topk_ndcg_rows<<<BQ, THREADS, 0, stream>>>(scores, mask, per_row);
    reduce_mean<<<1, 256, 0, stream>>>(per_row, (float*)d_out);
}